// Round 11
// baseline (239.929 us; speedup 1.0000x reference)
//
#include <hip/hip_runtime.h>
#include <cstdint>

// FeaturePropagation: BL=16, N=8192, N_sub=2048, dim=256, K=3, f32.
// R10: 121us, VALUBusy 89%. Back-solve: 31.5 VALU/cand; insert is exactly 8
// (asm), so the C++ distance+pack section emits ~23 VALU/cand for ~7 source
// ops. R11: the WHOLE per-candidate body is ONE asm block (14 VALU):
//   dist: v_add_f32 + 3x v_fma_f32      (t = a2+||s||^2 - 2q.s)
//   pack: v_and_b32 (lit src0) + v_or   (key = bits(t)&~0x7FF | idx)
//   insert: max/med3/min carry chain    (top-6, proven R9/R10)
// C++ keeps only the float4 LDS load + idx increment. Selection correctness
// unchanged: top-6 truncated-key proxy -> f64 re-rank (proven R4..R10).

#define NBL   16
#define NQ    8192
#define NS    2048
#define DIM   256
#define TPB   256   // threads per block
#define QPB   128   // queries per block (2 threads per query)

typedef float __attribute__((ext_vector_type(4))) f32x4;

__global__ __launch_bounds__(TPB, 4)
void fprop_kernel(const float* __restrict__ xyzs,
                  const float* __restrict__ feats,
                  const float* __restrict__ xyzo,
                  float* __restrict__ out) {
    __shared__ float4 sxyz[NS];          // 32 KiB: x, y, z, ||s||^2
    __shared__ int    mbuf[QPB][2][6];   // 6 KiB: per-query per-half top-6 keys;
                                         // mbuf[q][1][0..5] reused for results

    const int tid    = threadIdx.x;
    const int B      = blockIdx.x;
    const int xcd    = B & 7;                    // HW: XCD = blockIdx % 8
    const int blocal = B >> 3;                   // 0..127
    const int bl     = 2 * xcd + (blocal >> 6);  // 2 bl's per XCD
    const int qbase  = (blocal & 63) * QPB;

    // ---- Phase 0: stage candidates into LDS ----
    const float* xs = xyzs + (size_t)bl * NS * 3;
    for (int c = tid; c < NS; c += TPB) {
        float x = xs[c * 3 + 0];
        float y = xs[c * 3 + 1];
        float z = xs[c * 3 + 2];
        sxyz[c] = make_float4(x, y, z, fmaf(x, x, fmaf(y, y, z * z)));
    }
    __syncthreads();

    const int q = tid & (QPB - 1);
    const int h = tid >> 7;                      // wave-uniform: waves 0,1 vs 2,3

    int k0 = 0x7FFFFFFF, k1 = 0x7FFFFFFF, k2 = 0x7FFFFFFF;
    int k3 = 0x7FFFFFFF, k4 = 0x7FFFFFFF, k5 = 0x7FFFFFFF;

    // ---- Phase 1: half-scan; whole candidate body in one asm block ----
    const float* qp = xyzo + ((size_t)bl * NQ + qbase + q) * 3;
    const float qx = qp[0], qy = qp[1], qz = qp[2];
    {
        const float a2 = fmaf(qx, qx, fmaf(qy, qy, qz * qz));
        const float nx = -2.0f * qx, ny = -2.0f * qy, nz = -2.0f * qz;
        const int cbase = h << 10;               // h * 1024

        // 14 VALU: add,3xfma, and,or, max,med3,min, max,med3,min, med3,min
#define DIST_INS(S, IDX)                                                   \
        {   int cc, ct; float tt;                                          \
            asm("v_add_f32 %[tt], %[a2], %[sw]\n\t"                        \
                "v_fma_f32 %[tt], %[nz], %[sz], %[tt]\n\t"                 \
                "v_fma_f32 %[tt], %[ny], %[sy], %[tt]\n\t"                 \
                "v_fma_f32 %[tt], %[nx], %[sx], %[tt]\n\t"                 \
                "v_and_b32 %[tt], 0xFFFFF800, %[tt]\n\t"                   \
                "v_or_b32 %[cc], %[ix], %[tt]\n\t"                         \
                "v_max_i32 %[ct], %[k1], %[cc]\n\t"                        \
                "v_med3_i32 %[k1], %[k0], %[k1], %[cc]\n\t"                \
                "v_min_i32 %[k0], %[k0], %[cc]\n\t"                        \
                "v_max_i32 %[cc], %[k3], %[ct]\n\t"                        \
                "v_med3_i32 %[k3], %[k2], %[k3], %[ct]\n\t"                \
                "v_min_i32 %[k2], %[k2], %[ct]\n\t"                        \
                "v_med3_i32 %[k5], %[k4], %[k5], %[cc]\n\t"                \
                "v_min_i32 %[k4], %[k4], %[cc]"                            \
                : [k0]"+v"(k0), [k1]"+v"(k1), [k2]"+v"(k2),                \
                  [k3]"+v"(k3), [k4]"+v"(k4), [k5]"+v"(k5),                \
                  [cc]"=&v"(cc), [ct]"=&v"(ct), [tt]"=&v"(tt)              \
                : [sx]"v"((S).x), [sy]"v"((S).y), [sz]"v"((S).z),          \
                  [sw]"v"((S).w), [nx]"v"(nx), [ny]"v"(ny), [nz]"v"(nz),   \
                  [a2]"v"(a2), [ix]"v"(IDX));                              \
        }

#pragma unroll 4
        for (int c = 0; c < NS / 2; ++c) {
            const float4 s = sxyz[cbase + c];
            DIST_INS(s, cbase + c)
        }
#undef DIST_INS
        mbuf[q][h][0] = k0; mbuf[q][h][1] = k1; mbuf[q][h][2] = k2;
        mbuf[q][h][3] = k3; mbuf[q][h][4] = k4; mbuf[q][h][5] = k5;
    }
    __syncthreads();

    // ---- merge partner half's 6 keys (8-op insert, no dist) ----
#define INS6(CUR)                                                          \
    {   int cc = (CUR), ct;                                                \
        asm("v_max_i32 %[ct], %[k1], %[cc]\n\t"                            \
            "v_med3_i32 %[k1], %[k0], %[k1], %[cc]\n\t"                    \
            "v_min_i32 %[k0], %[k0], %[cc]\n\t"                            \
            "v_max_i32 %[cc], %[k3], %[ct]\n\t"                            \
            "v_med3_i32 %[k3], %[k2], %[k3], %[ct]\n\t"                    \
            "v_min_i32 %[k2], %[k2], %[ct]\n\t"                            \
            "v_med3_i32 %[k5], %[k4], %[k5], %[cc]\n\t"                    \
            "v_min_i32 %[k4], %[k4], %[cc]"                                \
            : [k0] "+v"(k0), [k1] "+v"(k1), [k2] "+v"(k2),                 \
              [k3] "+v"(k3), [k4] "+v"(k4), [k5] "+v"(k5),                 \
              [cc] "+v"(cc), [ct] "=&v"(ct)                                \
            :);                                                            \
    }
    {
        const int oh = h ^ 1;
#pragma unroll
        for (int j = 0; j < 6; ++j) INS6(mbuf[q][oh][j])
    }
#undef INS6

    // ---- exact f64 re-rank of the 6 survivors ----
    {
        int ii0 = k0 & 0x7FF, ii1 = k1 & 0x7FF, ii2 = k2 & 0x7FF;
        int ii3 = k3 & 0x7FF, ii4 = k4 & 0x7FF, ii5 = k5 & 0x7FF;
        const double qdx = (double)qx, qdy = (double)qy, qdz = (double)qz;
        double dd0, dd1, dd2, dd3, dd4, dd5;
#define D2OF(JJ, DD)                                                       \
        {                                                                  \
            const float4 s = sxyz[JJ];                                     \
            const double dx = qdx - (double)s.x;                           \
            const double dy = qdy - (double)s.y;                           \
            const double dz = qdz - (double)s.z;                           \
            DD = fma(dx, dx, fma(dy, dy, dz * dz));                        \
        }
        D2OF(ii0, dd0) D2OF(ii1, dd1) D2OF(ii2, dd2)
        D2OF(ii3, dd3) D2OF(ii4, dd4) D2OF(ii5, dd5)
#undef D2OF

#define CSW(A, B)                                                          \
        {                                                                  \
            const bool sw = (dd##B < dd##A) ||                             \
                            (dd##B == dd##A && ii##B < ii##A);             \
            const double td = sw ? dd##B : dd##A;                          \
            const double tu = sw ? dd##A : dd##B;                          \
            const int    ti = sw ? ii##B : ii##A;                          \
            const int    tj = sw ? ii##A : ii##B;                          \
            dd##A = td; dd##B = tu; ii##A = ti; ii##B = tj;                \
        }
        // optimal 12-comparator sorting network, n=6 (Knuth)
        CSW(0,5) CSW(1,3) CSW(2,4)
        CSW(1,2) CSW(3,4)
        CSW(0,3) CSW(2,5)
        CSW(0,1) CSW(2,3) CSW(4,5)
        CSW(1,2) CSW(3,4)
#undef CSW

        const double w0 = 1.0 / (dd0 + 1e-6);
        const double w1 = 1.0 / (dd1 + 1e-6);
        const double w2 = 1.0 / (dd2 + 1e-6);
        const double inv = 1.0 / (w0 + w1 + w2);
        // program-order safety: this thread already consumed mbuf[q][*];
        // no other thread reads mbuf[q][1] => h==0 may overwrite w/o barrier
        if (h == 0) {
            mbuf[q][1][0] = ii0; mbuf[q][1][1] = ii1; mbuf[q][1][2] = ii2;
            mbuf[q][1][3] = __float_as_int((float)(w0 * inv));
            mbuf[q][1][4] = __float_as_int((float)(w1 * inv));
            mbuf[q][1][5] = __float_as_int((float)(w2 * inv));
        }
    }
    __syncthreads();

    // ---- Phase 2: wave-per-query gather-blend (64 lanes x float4 = 256 dims) ----
    {
        const int wv   = tid >> 6;               // 0..3
        const int lane = tid & 63;
        const float4* fb = (const float4*)(feats + (size_t)bl * NS * DIM);
        float* ob = out + ((size_t)bl * NQ + qbase) * DIM;

#pragma unroll 2
        for (int j = wv; j < QPB; j += 4) {
            const int   i0 = mbuf[j][1][0], i1 = mbuf[j][1][1], i2 = mbuf[j][1][2];
            const float w0 = __int_as_float(mbuf[j][1][3]);
            const float w1 = __int_as_float(mbuf[j][1][4]);
            const float w2 = __int_as_float(mbuf[j][1][5]);
            const float4 f0 = fb[(size_t)i0 * (DIM / 4) + lane];
            const float4 f1 = fb[(size_t)i1 * (DIM / 4) + lane];
            const float4 f2 = fb[(size_t)i2 * (DIM / 4) + lane];
            f32x4 r;
            r.x = fmaf(w0, f0.x, fmaf(w1, f1.x, w2 * f2.x));
            r.y = fmaf(w0, f0.y, fmaf(w1, f1.y, w2 * f2.y));
            r.z = fmaf(w0, f0.z, fmaf(w1, f1.z, w2 * f2.z));
            r.w = fmaf(w0, f0.w, fmaf(w1, f1.w, w2 * f2.w));
            __builtin_nontemporal_store(
                r, (f32x4*)(ob + ((size_t)j * DIM) + lane * 4));
        }
    }
}

extern "C" void kernel_launch(void* const* d_in, const int* in_sizes, int n_in,
                              void* d_out, int out_size, void* d_ws, size_t ws_size,
                              hipStream_t stream) {
    const float* xyzs  = nullptr;  // 16*2048*3
    const float* feats = nullptr;  // 16*2048*256
    const float* xyzo  = nullptr;  // 16*8192*3
    for (int i = 0; i < n_in; ++i) {
        if      (in_sizes[i] == NBL * NS * 3)   xyzs  = (const float*)d_in[i];
        else if (in_sizes[i] == NBL * NS * DIM) feats = (const float*)d_in[i];
        else if (in_sizes[i] == NBL * NQ * 3)   xyzo  = (const float*)d_in[i];
    }
    float* out = (float*)d_out;

    dim3 grid(NBL * (NQ / QPB));                 // 1024 blocks
    dim3 block(TPB);                             // 256 threads
    fprop_kernel<<<grid, block, 0, stream>>>(xyzs, feats, xyzo, out);
}

// Round 12
// 230.866 us; speedup vs baseline: 1.0393x; 1.0393x over previous
//
#include <hip/hip_runtime.h>
#include <cstdint>

// FeaturePropagation: BL=16, N=8192, N_sub=2048, dim=256, K=3, f32.
// Evidence R5->R9: halving per-thread scan (2048->1024 cand) at constant
// total VALU work halved time (222->123us) => LATENCY-bound per wave, not
// VALU-throughput-bound (VALUBusy misattributes on gfx950). R10 vs R11:
// hand-asm of the whole body changed nothing => codegen already minimal.
// R12: 4-way split scan (512 cand/thread), h = tid>>6 wave-uniform so LDS
// candidate reads stay broadcast. QPB=64, TPB=256, grid 2048. Merge: wave 0
// folds the 3 partner lists (18 INS6, one-time). Selection pipeline
// unchanged (truncated-key top-6 -> f64 re-rank, proven R4..R11).

#define NBL   16
#define NQ    8192
#define NS    2048
#define DIM   256
#define TPB   256   // threads per block
#define QPB   64    // queries per block (4 threads per query)

typedef float __attribute__((ext_vector_type(4))) f32x4;

__global__ __launch_bounds__(TPB, 4)
void fprop_kernel(const float* __restrict__ xyzs,
                  const float* __restrict__ feats,
                  const float* __restrict__ xyzo,
                  float* __restrict__ out) {
    __shared__ float4 sxyz[NS];          // 32 KiB: x, y, z, ||s||^2
    __shared__ int    mbuf[QPB][4][6];   // 6 KiB: per-query per-quarter top-6;
                                         // mbuf[q][1][0..5] reused for results

    const int tid    = threadIdx.x;
    const int B      = blockIdx.x;
    const int xcd    = B & 7;                    // HW: XCD = blockIdx % 8
    const int blocal = B >> 3;                   // 0..255
    const int bl     = 2 * xcd + (blocal >> 7);  // 2 bl's per XCD
    const int qbase  = (blocal & 127) * QPB;

    // ---- Phase 0: stage candidates into LDS ----
    const float* xs = xyzs + (size_t)bl * NS * 3;
    for (int c = tid; c < NS; c += TPB) {
        float x = xs[c * 3 + 0];
        float y = xs[c * 3 + 1];
        float z = xs[c * 3 + 2];
        sxyz[c] = make_float4(x, y, z, fmaf(x, x, fmaf(y, y, z * z)));
    }
    __syncthreads();

    const int q = tid & (QPB - 1);
    const int h = tid >> 6;                      // wave index 0..3 (wave-uniform)

    int k0 = 0x7FFFFFFF, k1 = 0x7FFFFFFF, k2 = 0x7FFFFFFF;
    int k3 = 0x7FFFFFFF, k4 = 0x7FFFFFFF, k5 = 0x7FFFFFFF;

    // Branchless sorted-6 insert, ONE asm block (8 VALU, no movs).
    // Pair (ka<=kb) + incoming c: carry=max(kb,c) FIRST, then
    // kb=med3(ka,kb,c), ka=min(ka,c); carry alternates cc <-> ct.
#define INS6(CUR)                                                          \
    {   int cc = (CUR), ct;                                                \
        asm("v_max_i32 %[ct], %[k1], %[cc]\n\t"                            \
            "v_med3_i32 %[k1], %[k0], %[k1], %[cc]\n\t"                    \
            "v_min_i32 %[k0], %[k0], %[cc]\n\t"                            \
            "v_max_i32 %[cc], %[k3], %[ct]\n\t"                            \
            "v_med3_i32 %[k3], %[k2], %[k3], %[ct]\n\t"                    \
            "v_min_i32 %[k2], %[k2], %[ct]\n\t"                            \
            "v_med3_i32 %[k5], %[k4], %[k5], %[cc]\n\t"                    \
            "v_min_i32 %[k4], %[k4], %[cc]"                                \
            : [k0] "+v"(k0), [k1] "+v"(k1), [k2] "+v"(k2),                 \
              [k3] "+v"(k3), [k4] "+v"(k4), [k5] "+v"(k5),                 \
              [cc] "+v"(cc), [ct] "=&v"(ct)                                \
            :);                                                            \
    }

    // ---- Phase 1: quarter-scan, branchless top-6 of packed (d2,idx) keys ----
    const float* qp = xyzo + ((size_t)bl * NQ + qbase + q) * 3;
    const float qx = qp[0], qy = qp[1], qz = qp[2];
    {
        const float a2 = fmaf(qx, qx, fmaf(qy, qy, qz * qz));
        const float nx = -2.0f * qx, ny = -2.0f * qy, nz = -2.0f * qz;
        const int cbase = h << 9;                // h * 512

#pragma unroll 4
        for (int c = 0; c < NS / 4; ++c) {
            const float4 s = sxyz[cbase + c];
            const float t = fmaf(nx, s.x, fmaf(ny, s.y, fmaf(nz, s.z, a2 + s.w)));
            const int cur = (int)((__float_as_uint(t) & 0xFFFFF800u) |
                                  (uint32_t)(cbase + c));
            INS6(cur)
        }
        mbuf[q][h][0] = k0; mbuf[q][h][1] = k1; mbuf[q][h][2] = k2;
        mbuf[q][h][3] = k3; mbuf[q][h][4] = k4; mbuf[q][h][5] = k5;
    }
    __syncthreads();

    // ---- wave 0 only: merge partners' lists, f64 re-rank, publish ----
    if (h == 0) {
#pragma unroll
        for (int hh = 1; hh < 4; ++hh)
#pragma unroll
            for (int j = 0; j < 6; ++j) INS6(mbuf[q][hh][j])

        int ii0 = k0 & 0x7FF, ii1 = k1 & 0x7FF, ii2 = k2 & 0x7FF;
        int ii3 = k3 & 0x7FF, ii4 = k4 & 0x7FF, ii5 = k5 & 0x7FF;
        const double qdx = (double)qx, qdy = (double)qy, qdz = (double)qz;
        double dd0, dd1, dd2, dd3, dd4, dd5;
#define D2OF(JJ, DD)                                                       \
        {                                                                  \
            const float4 s = sxyz[JJ];                                     \
            const double dx = qdx - (double)s.x;                           \
            const double dy = qdy - (double)s.y;                           \
            const double dz = qdz - (double)s.z;                           \
            DD = fma(dx, dx, fma(dy, dy, dz * dz));                        \
        }
        D2OF(ii0, dd0) D2OF(ii1, dd1) D2OF(ii2, dd2)
        D2OF(ii3, dd3) D2OF(ii4, dd4) D2OF(ii5, dd5)
#undef D2OF

#define CSW(A, B)                                                          \
        {                                                                  \
            const bool sw = (dd##B < dd##A) ||                             \
                            (dd##B == dd##A && ii##B < ii##A);             \
            const double td = sw ? dd##B : dd##A;                          \
            const double tu = sw ? dd##A : dd##B;                          \
            const int    ti = sw ? ii##B : ii##A;                          \
            const int    tj = sw ? ii##A : ii##B;                          \
            dd##A = td; dd##B = tu; ii##A = ti; ii##B = tj;                \
        }
        // optimal 12-comparator sorting network, n=6 (Knuth)
        CSW(0,5) CSW(1,3) CSW(2,4)
        CSW(1,2) CSW(3,4)
        CSW(0,3) CSW(2,5)
        CSW(0,1) CSW(2,3) CSW(4,5)
        CSW(1,2) CSW(3,4)
#undef CSW

        const double w0 = 1.0 / (dd0 + 1e-6);
        const double w1 = 1.0 / (dd1 + 1e-6);
        const double w2 = 1.0 / (dd2 + 1e-6);
        const double inv = 1.0 / (w0 + w1 + w2);
        // safe: only this thread (q, h=0) reads mbuf[q][*] between barriers,
        // and it has already consumed them => in-place publish, no race
        mbuf[q][1][0] = ii0; mbuf[q][1][1] = ii1; mbuf[q][1][2] = ii2;
        mbuf[q][1][3] = __float_as_int((float)(w0 * inv));
        mbuf[q][1][4] = __float_as_int((float)(w1 * inv));
        mbuf[q][1][5] = __float_as_int((float)(w2 * inv));
    }
#undef INS6
    __syncthreads();

    // ---- Phase 2: wave-per-query gather-blend (64 lanes x float4 = 256 dims) ----
    {
        const int wv   = tid >> 6;               // 0..3
        const int lane = tid & 63;
        const float4* fb = (const float4*)(feats + (size_t)bl * NS * DIM);
        float* ob = out + ((size_t)bl * NQ + qbase) * DIM;

#pragma unroll 2
        for (int j = wv; j < QPB; j += 4) {
            const int   i0 = mbuf[j][1][0], i1 = mbuf[j][1][1], i2 = mbuf[j][1][2];
            const float w0 = __int_as_float(mbuf[j][1][3]);
            const float w1 = __int_as_float(mbuf[j][1][4]);
            const float w2 = __int_as_float(mbuf[j][1][5]);
            const float4 f0 = fb[(size_t)i0 * (DIM / 4) + lane];
            const float4 f1 = fb[(size_t)i1 * (DIM / 4) + lane];
            const float4 f2 = fb[(size_t)i2 * (DIM / 4) + lane];
            f32x4 r;
            r.x = fmaf(w0, f0.x, fmaf(w1, f1.x, w2 * f2.x));
            r.y = fmaf(w0, f0.y, fmaf(w1, f1.y, w2 * f2.y));
            r.z = fmaf(w0, f0.z, fmaf(w1, f1.z, w2 * f2.z));
            r.w = fmaf(w0, f0.w, fmaf(w1, f1.w, w2 * f2.w));
            __builtin_nontemporal_store(
                r, (f32x4*)(ob + ((size_t)j * DIM) + lane * 4));
        }
    }
}

extern "C" void kernel_launch(void* const* d_in, const int* in_sizes, int n_in,
                              void* d_out, int out_size, void* d_ws, size_t ws_size,
                              hipStream_t stream) {
    const float* xyzs  = nullptr;  // 16*2048*3
    const float* feats = nullptr;  // 16*2048*256
    const float* xyzo  = nullptr;  // 16*8192*3
    for (int i = 0; i < n_in; ++i) {
        if      (in_sizes[i] == NBL * NS * 3)   xyzs  = (const float*)d_in[i];
        else if (in_sizes[i] == NBL * NS * DIM) feats = (const float*)d_in[i];
        else if (in_sizes[i] == NBL * NQ * 3)   xyzo  = (const float*)d_in[i];
    }
    float* out = (float*)d_out;

    dim3 grid(NBL * (NQ / QPB));                 // 2048 blocks
    dim3 block(TPB);                             // 256 threads
    fprop_kernel<<<grid, block, 0, stream>>>(xyzs, feats, xyzo, out);
}